// Round 10
// baseline (196.322 us; speedup 1.0000x reference)
//
#include <hip/hip_runtime.h>
#include <hip/hip_bf16.h>
#include <cstdint>

typedef __bf16 bf16_t;
typedef bf16_t bf16x8 __attribute__((ext_vector_type(8)));
typedef bf16_t bf16x4 __attribute__((ext_vector_type(4)));
typedef float  f32x4  __attribute__((ext_vector_type(4)));

#define S0 512
#define S1 256
#define S2 128
#define NGRID 128
#define GPTS (NGRID*NGRID)   // 16384

// workspace layout (bytes)
#define WS_BASE  0u          // 16*512 f32            = 32 KB
#define WS_W1P   32768u      // 262144*8 bf16         = 4 MB
#define WS_W2P   4227072u    // 65536*8 bf16          = 1 MB
#define WS_W3P   5275648u    // 4096*8 bf16           = 64 KB
#define WS_BASEC 5341184u    // 16*512 f32 compacted  = 32 KB
#define WS_WXYC  5373952u    // 16*512*2 f32          = 64 KB
#define WS_IDX   5439488u    // 16*512 int            = 32 KB
#define WS_LIN   5472256u    // 16*512 int            = 32 KB
#define WS_F     5505024u    // 16*256*4 f32          = 64 KB
#define WS_CNT   5570560u    // Kc[16] + nlin[16]

__device__ __forceinline__ float tanh_fast(float x) {
  float e = __builtin_amdgcn_exp2f(x * 2.88539008f);   // 2*log2(e)
  return fmaf(-2.0f, __builtin_amdgcn_rcpf(e + 1.0f), 1.0f);
}

// h1 LDS tile [128 rows][256 cols] bf16, 64 KB exactly (no pad possible) ->
// T2 XOR swizzle keeps stride-512B column reads 2-way-conflict-free:
//   phys_byte(row,col) = row*512 + ((col*2) ^ ((row&7)<<4))
__device__ __forceinline__ bf16x8 ld_h1(const bf16_t* s, int row, int colk) {
  const int byte = row*512 + (((colk*2) ^ ((row & 7) << 4)));
  return *(const bf16x8*)((const char*)s + byte);
}
__device__ __forceinline__ void st_h1(bf16_t* s, int row, int col, bf16x4 v) {
  const int byte = row*512 + (((col*2) ^ ((row & 7) << 4)));
  *(bf16x4*)((char*)s + byte) = v;
}

// ---------------------------------------------------------------------------
// Launch 1: blocks [0,2048): base[m][o] = W0a·x0 + b0a + b0b  (fp32)
//           blocks [2048,2368): pack W2/W3 into bf16 MFMA B-frag order
// ---------------------------------------------------------------------------
__global__ __launch_bounds__(256) void prep_a(
    const float* __restrict__ x0, const float* __restrict__ W0a,
    const float* __restrict__ b0a, const float* __restrict__ b0b,
    const float* __restrict__ W2, const float* __restrict__ W3,
    float* __restrict__ base, bf16_t* __restrict__ W2p, bf16_t* __restrict__ W3p)
{
  if (blockIdx.x < 2048) {
    int wid = (blockIdx.x << 2) + (threadIdx.x >> 6);   // 0..8191
    int L = threadIdx.x & 63;
    int m = wid >> 9, o = wid & 511;
    const float* wrow = W0a + ((size_t)(m*S0 + o) << 10);
    float acc = 0.f;
#pragma unroll
    for (int i = 0; i < 4; ++i) {
      f32x4 wv = *(const f32x4*)(wrow + i*256 + L*4);
      f32x4 xv = *(const f32x4*)(x0   + i*256 + L*4);
      acc += wv.x*xv.x + wv.y*xv.y + wv.z*xv.z + wv.w*xv.w;
    }
#pragma unroll
    for (int s = 32; s; s >>= 1) acc += __shfl_xor(acc, s, 64);
    if (L == 0) base[m*S0 + o] = acc + b0a[m*S0 + o] + b0b[m*S0 + o];
    return;
  }

  int T = (blockIdx.x - 2048) * 256 + threadIdx.x;  // 81920 total
  const float* src = nullptr;
  bf16_t* dst = nullptr;
  if (T < 65536) {                  // W2: 16m * 8ks * 8nt * 64L
    int L = T & 63, nt = (T >> 6) & 7, ks = (T >> 9) & 7, m = T >> 12;
    int n = nt*16 + (L & 15), k0 = ks*32 + ((L >> 4) & 3)*8;
    src = W2 + (size_t)(m*S2 + n)*S1 + k0;
    dst = W2p + (size_t)T*8;
  } else {                          // W3: 16m * 4ks * 1nt * 64L (N padded to 16)
    int T3 = T - 65536;
    int L = T3 & 63, ks = (T3 >> 6) & 3, m = T3 >> 8;
    int n = L & 15, k0 = ks*32 + ((L >> 4) & 3)*8;
    dst = W3p + (size_t)T3*8;
    if (n < 3) src = W3 + (size_t)(m*3 + n)*S2 + k0;
  }
  bf16x8 v;
  if (src) {
    f32x4 a = *(const f32x4*)src;
    f32x4 b = *(const f32x4*)(src + 4);
    v[0]=(bf16_t)a.x; v[1]=(bf16_t)a.y; v[2]=(bf16_t)a.z; v[3]=(bf16_t)a.w;
    v[4]=(bf16_t)b.x; v[5]=(bf16_t)b.y; v[6]=(bf16_t)b.z; v[7]=(bf16_t)b.w;
  } else {
#pragma unroll
    for (int j = 0; j < 8; ++j) v[j] = (bf16_t)0.f;
  }
  *(bf16x8*)dst = v;
}

// ---------------------------------------------------------------------------
// Launch 2: per-m channel classification over the full grid [-1,1]^2.
//   dead   : base + |wx| + |wy| <= 0  -> relu == 0 everywhere -> drop
//   linear : base - |wx| - |wy| >= 0  -> relu == identity     -> fold (rank-1)
//   active : the rest -> compacted (idx, basec, wxyc) for the MFMA path
// ---------------------------------------------------------------------------
__global__ __launch_bounds__(256) void classify_k(
    const float* __restrict__ base, const float* __restrict__ W0b,
    float* __restrict__ basec, float* __restrict__ wxyc,
    int* __restrict__ idx, int* __restrict__ lin,
    int* __restrict__ Kc, int* __restrict__ nlin, float* __restrict__ F)
{
  __shared__ int sc[512];
  const int m = blockIdx.x, t = threadIdx.x;
  float b[2], wx[2], wy[2]; int fa[2], fl[2];
#pragma unroll
  for (int h = 0; h < 2; ++h) {
    const int k = t + h*256;
    b[h]  = base[m*S0 + k];
    wx[h] = W0b[(m*S0 + k)*2];
    wy[h] = W0b[(m*S0 + k)*2 + 1];
    const float aw = fabsf(wx[h]) + fabsf(wy[h]);
    const int dead = (b[h] + aw) <= 0.f;
    fl[h] = (!dead) && ((b[h] - aw) >= 0.f);
    fa[h] = (!dead) && (!fl[h]);
    sc[k] = fa[h] | (fl[h] << 16);
  }
  __syncthreads();
  for (int off = 1; off < 512; off <<= 1) {
    int v0 = sc[t], v1 = sc[t+256];
    int u0 = (t >= off) ? sc[t-off] : 0;
    int u1 = (t+256 >= off) ? sc[t+256-off] : 0;
    __syncthreads();
    sc[t] = v0 + u0; sc[t+256] = v1 + u1;
    __syncthreads();
  }
  const int tot = sc[511];
  const int KcM = tot & 0xffff, nlM = tot >> 16;
#pragma unroll
  for (int h = 0; h < 2; ++h) {
    const int k = t + h*256;
    const int incl = sc[k];
    if (fa[h]) {
      const int p = (incl & 0xffff) - 1;
      idx[m*S0 + p] = k;
      basec[m*S0 + p] = b[h];
      wxyc[m*S0*2 + 2*p]     = wx[h];
      wxyc[m*S0*2 + 2*p + 1] = wy[h];
    } else if (fl[h]) {
      lin[m*S0 + ((incl >> 16) - 1)] = k;
    }
  }
  // zero tails (slots >= KcM are disjoint from the active writes above)
  for (int s = t; s < 512; s += 256) {
    if (s >= KcM) {
      idx[m*S0 + s] = 0;
      basec[m*S0 + s] = 0.f;
      wxyc[m*S0*2 + 2*s] = 0.f;
      wxyc[m*S0*2 + 2*s + 1] = 0.f;
    }
  }
  for (int i = t; i < 1024; i += 256) F[m*1024 + i] = 0.f;  // fold accumulators
  if (t == 0) { Kc[m] = KcM; nlin[m] = nlM; }
}

// ---------------------------------------------------------------------------
// Launch 3: gather-pack W1 (zero-filled tails) + fold linear channels into F.
// ---------------------------------------------------------------------------
__global__ __launch_bounds__(256) void prep_b(
    const float* __restrict__ W1, const float* __restrict__ base,
    const float* __restrict__ W0b,
    const int* __restrict__ idx, const int* __restrict__ lin,
    const int* __restrict__ Kc, const int* __restrict__ nlin,
    bf16_t* __restrict__ W1p, float* __restrict__ F)
{
  if (blockIdx.x < 1024) {
    const int T = blockIdx.x*256 + threadIdx.x;   // < 262144
    const int L = T & 63, nt = (T >> 6) & 15, ks = (T >> 10) & 15, m = T >> 14;
    const int KcM = Kc[m];
    const int n = nt*16 + (L & 15), kb = ks*32 + ((L >> 4) & 3)*8;
    const float* wrow = W1 + (size_t)(m*S1 + n)*S0;
    const int* ip = idx + m*S0 + kb;
    bf16x8 v;
#pragma unroll
    for (int j = 0; j < 8; ++j)
      v[j] = (kb + j < KcM) ? (bf16_t)wrow[ip[j]] : (bf16_t)0.f;
    *(bf16x8*)(W1p + (size_t)T*8) = v;
  } else {
    const int b2 = blockIdx.x - 1024;              // 0..255
    const int m = b2 >> 4, s = b2 & 15, n = threadIdx.x;
    const int nl = nlin[m];
    float a0 = 0.f, ax = 0.f, ay = 0.f;
    const float* wrow = W1 + (size_t)(m*S1 + n)*S0;
    for (int j = s; j < nl; j += 16) {
      const int k = lin[m*S0 + j];
      const float w = wrow[k];
      a0 = fmaf(w, base[m*S0 + k], a0);
      ax = fmaf(w, W0b[(m*S0 + k)*2], ax);
      ay = fmaf(w, W0b[(m*S0 + k)*2 + 1], ay);
    }
    float* fp = F + ((size_t)m*S1 + n)*4;
    atomicAdd(fp + 0, a0);
    atomicAdd(fp + 1, ax);
    atomicAdd(fp + 2, ay);
  }
}

// ---------------------------------------------------------------------------
// L1 K-loop, 128-row tile, static trip NKS, BARRIER-FREE / LDS-FREE:
// wave w = (rh = w>>1: row-blocks rh*4..rh*4+3, ch = w&1: cols ch*128..+127).
// Round-9 post-mortem: the LDS A-share made the LDS pipe the bottleneck
// (8 waves x 8 ds_read_b128 x ~12cyc ~ 770 cyc/chunk/CU vs ~310 MFMA).
// Here each lane generates its OWN A-fragments in registers: the gen inputs
// t[j]/wx[j] are lane-local (k = kk + quad*8 + j) and xr is a scalar per
// row-block -> af[i][j] = relu(fma(wx[j], xr_i, t[j])). 2x gen redundancy
// (vs 4x in round 2) but ZERO LDS traffic and ZERO barriers in L1 -> waves
// and the 2 co-resident WGs dephase freely; VALU/MFMA/L2 pipes overlap.
// B double-buffered in registers (8+8 frags); acc1[4][8] = 128 AGPR.
// ---------------------------------------------------------------------------
template<int NKS>
__device__ __forceinline__ void l1_compute(
    const bf16_t* __restrict__ bp1, const float* __restrict__ bc,
    const float* __restrict__ wc, const int quad,
    const float yv, const float xr0, const float step16,
    f32x4 (&acc1)[4][8])
{
  bf16x8 Bc[8], Bn[8];
#pragma unroll
  for (int n = 0; n < 8; ++n) Bc[n] = *(const bf16x8*)(bp1 + (size_t)n*512);

#pragma unroll 2
  for (int ks = 0; ks < NKS; ++ks) {
    // issue next-chunk B loads first: a full chunk of compute covers L2 latency
    if (ks + 1 < NKS) {
#pragma unroll
      for (int n = 0; n < 8; ++n)
        Bn[n] = *(const bf16x8*)(bp1 + (size_t)(ks+1)*8192 + (size_t)n*512);
    }
    const int kk = ks*32 + quad*8;
    f32x4 cA  = *(const f32x4*)(bc + kk);
    f32x4 cB  = *(const f32x4*)(bc + kk + 4);
    f32x4 wv0 = *(const f32x4*)(wc + kk*2);
    f32x4 wv1 = *(const f32x4*)(wc + kk*2 + 4);
    f32x4 wv2 = *(const f32x4*)(wc + kk*2 + 8);
    f32x4 wv3 = *(const f32x4*)(wc + kk*2 + 12);

    float t[8], wx[8];
    t[0] = fmaf(wv0.y, yv, cA.x); wx[0] = wv0.x;
    t[1] = fmaf(wv0.w, yv, cA.y); wx[1] = wv0.z;
    t[2] = fmaf(wv1.y, yv, cA.z); wx[2] = wv1.x;
    t[3] = fmaf(wv1.w, yv, cA.w); wx[3] = wv1.z;
    t[4] = fmaf(wv2.y, yv, cB.x); wx[4] = wv2.x;
    t[5] = fmaf(wv2.w, yv, cB.y); wx[5] = wv2.z;
    t[6] = fmaf(wv3.y, yv, cB.z); wx[6] = wv3.x;
    t[7] = fmaf(wv3.w, yv, cB.w); wx[7] = wv3.z;

#pragma unroll
    for (int i = 0; i < 4; ++i) {
      const float xr = xr0 + (float)i * step16;
      bf16x8 af;
#pragma unroll
      for (int j = 0; j < 8; ++j)
        af[j] = (bf16_t)fmaxf(fmaf(wx[j], xr, t[j]), 0.f);
#pragma unroll
      for (int n = 0; n < 8; ++n)
        acc1[i][n] = __builtin_amdgcn_mfma_f32_16x16x32_bf16(Bc[n], af, acc1[i][n], 0, 0, 0);
    }
    if (ks + 1 < NKS) {
#pragma unroll
      for (int n = 0; n < 8; ++n) Bc[n] = Bn[n];
    }
  }
}

// ---------------------------------------------------------------------------
// Fused MLP, 128-row supertile: WG = (m = bid>>7, grid row-line st = bid&127).
// 4 waves. L1: wave = (row-half rh, col-half ch), barrier-free in-register
// A-gen, acc1[4][8] (128 AGPR). L2/L3 unchanged: wave = col quarter over the
// h1 LDS tile (T2 XOR swizzle). (256,2): 2 WGs/CU, 64 KB LDS.
// L1 compacted (nks = ceil(Kc/32) chunks, static trip via switch); linear
// channels folded in the epilogue (F0 + Fx*x + Fy*y). MFMA (B,A)-swapped ->
// D = C^T. Frags: A/B row/col = lane&15, k = (lane>>4)*8+j;
// C/D: col = lane&15, row = quad*4+p.
// ---------------------------------------------------------------------------
__global__ __launch_bounds__(256, 2) void fused_mlp_k(
    const float* __restrict__ basec, const float* __restrict__ wxyc,
    const float* __restrict__ F, const int* __restrict__ Kc,
    const bf16_t* __restrict__ W1p, const bf16_t* __restrict__ W2p,
    const bf16_t* __restrict__ W3p,
    const float* __restrict__ b1, const float* __restrict__ b2,
    const float* __restrict__ b3, float* __restrict__ out)
{
  __shared__ __align__(16) bf16_t sLDS[128*256];  // 64 KB: h1 swizzled, then h2

  const int bid = blockIdx.x;
  const int m   = bid >> 7;             // m-major: L2-resident weights
  const int st  = bid & 127;            // grid row-line (y index)

  const int tid  = threadIdx.x;
  const int w    = tid >> 6, L = tid & 63;
  const int quad = L >> 4, lrow = L & 15;
  const int rh   = w >> 1;              // L1 row half (blocks rh*4 .. rh*4+3)
  const int ch   = w & 1;               // L1 col half (cols ch*128 .. +127)

  const float step = 2.0f / 127.0f;
  const float yv  = -1.0f + (float)st * step;
  const float xv0 = -1.0f + (float)lrow * step;          // x at row=lrow
  const float xr0 = xv0 + (float)(rh*64)*step;           // row-block rh*4
  const float step16 = 16.0f*step;

  const float* bc = basec + m*S0;
  const float* wc = wxyc + m*(S0*2);
  const int nks = (Kc[m] + 31) >> 5;    // compacted K-chunks (~10 of 16)

  f32x4 zero = {0.f, 0.f, 0.f, 0.f};
  f32x4 acc1[4][8];
#pragma unroll
  for (int a = 0; a < 4; ++a)
#pragma unroll
    for (int b = 0; b < 8; ++b) acc1[a][b] = zero;

  // ---------------- Layer 1: static-trip compacted K-loop ----------------
  const bf16_t* bp1 = W1p + (((size_t)(m*16)*16 + ch*8)*64 + L)*8;
#define L1_CASE(NN) case NN: l1_compute<NN>(bp1, bc, wc, quad, yv, xr0, step16, acc1); break;
  switch (nks) {
    L1_CASE(16) L1_CASE(15) L1_CASE(14) L1_CASE(13)
    L1_CASE(12) L1_CASE(11) L1_CASE(10) L1_CASE(9)
    L1_CASE(8)  L1_CASE(7)  L1_CASE(6)  L1_CASE(5)
    L1_CASE(4)  L1_CASE(3)  L1_CASE(2)  L1_CASE(1)
    default: break;   // nks == 0: all channels dead/linear, acc stays 0
  }
#undef L1_CASE

  // L1 epilogue: bias + linear fold (F0 + Fx*x + Fy*y), relu, D^T ->
  // thread holds 4 contiguous cols -> 8B swizzled stores
#pragma unroll
  for (int nb = 0; nb < 8; ++nb) {
    const int col = ch*128 + nb*16 + quad*4;
    f32x4 bb = *(const f32x4*)(b1 + m*S1 + col);
    float cterm[4], fx[4];
#pragma unroll
    for (int p = 0; p < 4; ++p) {
      f32x4 Fv = *(const f32x4*)(F + ((size_t)m*S1 + col + p)*4);
      cterm[p] = fmaf(Fv.z, yv, bb[p] + Fv.x);   // b1 + F0 + Fy*y
      fx[p] = Fv.y;
    }
#pragma unroll
    for (int i = 0; i < 4; ++i) {
      const int rb  = rh*4 + i;
      const int row = rb*16 + lrow;
      const float xr = xv0 + (float)(rb*16)*step;
      bf16x4 v;
#pragma unroll
      for (int p = 0; p < 4; ++p)
        v[p] = (bf16_t)fmaxf(acc1[i][nb][p] + fmaf(fx[p], xr, cterm[p]), 0.f);
      st_h1(sLDS, row, col, v);
    }
  }
  __syncthreads();

  // ---------------- Layer 2: K=256, 8 chunks, 16 MFMAs each ----------------
  f32x4 acc2[8][2];
#pragma unroll
  for (int a = 0; a < 8; ++a) { acc2[a][0] = zero; acc2[a][1] = zero; }
  const bf16_t* bp2 = W2p + (((size_t)(m*8)*8 + w*2)*64 + L)*8;
#pragma unroll 2
  for (int ks = 0; ks < 8; ++ks) {
    const int k2 = ks*32 + quad*8;
    bf16x8 b0f = *(const bf16x8*)(bp2 + (size_t)ks*4096);
    bf16x8 b1f = *(const bf16x8*)(bp2 + (size_t)ks*4096 + 512);
#pragma unroll
    for (int mt = 0; mt < 8; ++mt) {
      bf16x8 af = ld_h1(sLDS, mt*16 + lrow, k2);
      acc2[mt][0] = __builtin_amdgcn_mfma_f32_16x16x32_bf16(b0f, af, acc2[mt][0], 0, 0, 0);
      acc2[mt][1] = __builtin_amdgcn_mfma_f32_16x16x32_bf16(b1f, af, acc2[mt][1], 0, 0, 0);
    }
  }
  __syncthreads();   // all h1 reads done before aliased h2 writes

  // L2 epilogue: h2 -> sH2 [128][136], packed b64 stores
  bf16_t* sH2 = sLDS;
#pragma unroll
  for (int nb = 0; nb < 2; ++nb) {
    const int col = w*32 + nb*16 + quad*4;
    f32x4 bb = *(const f32x4*)(b2 + m*S2 + col);
#pragma unroll
    for (int mt = 0; mt < 8; ++mt) {
      const int row = mt*16 + lrow;
      bf16x4 v;
#pragma unroll
      for (int p = 0; p < 4; ++p)
        v[p] = (bf16_t)fmaxf(acc2[mt][nb][p] + bb[p], 0.f);
      *(bf16x4*)(&sH2[row*136 + col]) = v;
    }
  }
  __syncthreads();

  // ---------------- Layer 3: K=128; wave w does row-blocks w and w+4 ----------------
  f32x4 acc3[2] = {zero, zero};
#pragma unroll
  for (int ks = 0; ks < 4; ++ks) {
    bf16x8 bfr = *(const bf16x8*)(W3p + (((size_t)m*4 + ks)*64 + L)*8);
    bf16x8 af0 = *(const bf16x8*)(&sH2[((w  )*16 + lrow)*136 + ks*32 + quad*8]);
    bf16x8 af1 = *(const bf16x8*)(&sH2[((w+4)*16 + lrow)*136 + ks*32 + quad*8]);
    acc3[0] = __builtin_amdgcn_mfma_f32_16x16x32_bf16(bfr, af0, acc3[0], 0, 0, 0);
    acc3[1] = __builtin_amdgcn_mfma_f32_16x16x32_bf16(bfr, af1, acc3[1], 0, 0, 0);
  }
  if (quad == 0) {   // thread holds channels p=0..3 for its grid rows
#pragma unroll
    for (int ri = 0; ri < 2; ++ri) {
      const int rb = w + ri*4;
      const size_t o = ((size_t)m*GPTS + (size_t)st*128 + rb*16 + lrow)*3;
      out[o + 0] = tanh_fast(acc3[ri][0] + b3[m*3 + 0]);
      out[o + 1] = tanh_fast(acc3[ri][1] + b3[m*3 + 1]);
      out[o + 2] = tanh_fast(acc3[ri][2] + b3[m*3 + 2]);
    }
  }
}

// ---------------------------------------------------------------------------
extern "C" void kernel_launch(void* const* d_in, const int* in_sizes, int n_in,
                              void* d_out, int out_size, void* d_ws, size_t ws_size,
                              hipStream_t stream) {
  const float* x0  = (const float*)d_in[0];
  const float* W0a = (const float*)d_in[1];
  const float* b0a = (const float*)d_in[2];
  const float* W0b = (const float*)d_in[3];
  const float* b0b = (const float*)d_in[4];
  const float* W1  = (const float*)d_in[5];
  const float* b1  = (const float*)d_in[6];
  const float* W2  = (const float*)d_in[7];
  const float* b2  = (const float*)d_in[8];
  const float* W3  = (const float*)d_in[9];
  const float* b3  = (const float*)d_in[10];

  char* ws = (char*)d_ws;
  float*  base  = (float*)(ws + WS_BASE);
  bf16_t* W1p   = (bf16_t*)(ws + WS_W1P);
  bf16_t* W2p   = (bf16_t*)(ws + WS_W2P);
  bf16_t* W3p   = (bf16_t*)(ws + WS_W3P);
  float*  basec = (float*)(ws + WS_BASEC);
  float*  wxyc  = (float*)(ws + WS_WXYC);
  int*    idx   = (int*)(ws + WS_IDX);
  int*    lin   = (int*)(ws + WS_LIN);
  float*  F     = (float*)(ws + WS_F);
  int*    Kc    = (int*)(ws + WS_CNT);
  int*    nlin  = (int*)(ws + WS_CNT + 64);
  float*  out   = (float*)d_out;

  prep_a<<<2368, 256, 0, stream>>>(x0, W0a, b0a, b0b, W2, W3, base, W2p, W3p);
  classify_k<<<16, 256, 0, stream>>>(base, W0b, basec, wxyc, idx, lin, Kc, nlin, F);
  prep_b<<<1280, 256, 0, stream>>>(W1, base, W0b, idx, lin, Kc, nlin, W1p, F);
  fused_mlp_k<<<2048, 256, 0, stream>>>(basec, wxyc, F, Kc, W1p, W2p, W3p, b1, b2, b3, out);
}

// Round 11
// 187.983 us; speedup vs baseline: 1.0444x; 1.0444x over previous
//
#include <hip/hip_runtime.h>
#include <hip/hip_bf16.h>
#include <cstdint>

typedef __bf16 bf16_t;
typedef bf16_t bf16x8 __attribute__((ext_vector_type(8)));
typedef bf16_t bf16x4 __attribute__((ext_vector_type(4)));
typedef float  f32x4  __attribute__((ext_vector_type(4)));

#define S0 512
#define S1 256
#define S2 128
#define NGRID 128
#define GPTS (NGRID*NGRID)   // 16384

// workspace layout (bytes)
#define WS_BASE  0u          // 16*512 f32            = 32 KB
#define WS_W1P   32768u      // 262144*8 bf16         = 4 MB
#define WS_W2P   4227072u    // 65536*8 bf16          = 1 MB
#define WS_W3P   5275648u    // 4096*8 bf16           = 64 KB
#define WS_BASEC 5341184u    // 16*512 f32 compacted  = 32 KB
#define WS_WXYC  5373952u    // 16*512*2 f32          = 64 KB
#define WS_IDX   5439488u    // 16*512 int            = 32 KB
#define WS_LIN   5472256u    // 16*512 int            = 32 KB
#define WS_F     5505024u    // 16*256*4 f32          = 64 KB
#define WS_CNT   5570560u    // Kc[16] + nlin[16]

__device__ __forceinline__ float tanh_fast(float x) {
  float e = __builtin_amdgcn_exp2f(x * 2.88539008f);   // 2*log2(e)
  return fmaf(-2.0f, __builtin_amdgcn_rcpf(e + 1.0f), 1.0f);
}

// h1 LDS tile [128 rows][256 cols] bf16, 64 KB exactly (no pad possible) ->
// T2 XOR swizzle keeps stride-512B column reads 2-way-conflict-free:
//   phys_byte(row,col) = row*512 + ((col*2) ^ ((row&7)<<4))
__device__ __forceinline__ bf16x8 ld_h1(const bf16_t* s, int row, int colk) {
  const int byte = row*512 + (((colk*2) ^ ((row & 7) << 4)));
  return *(const bf16x8*)((const char*)s + byte);
}
__device__ __forceinline__ void st_h1(bf16_t* s, int row, int col, bf16x4 v) {
  const int byte = row*512 + (((col*2) ^ ((row & 7) << 4)));
  *(bf16x4*)((char*)s + byte) = v;
}

// ---------------------------------------------------------------------------
// Launch 1: blocks [0,2048): base[m][o] = W0a·x0 + b0a + b0b  (fp32)
//           blocks [2048,2368): pack W2/W3 into bf16 MFMA B-frag order
// ---------------------------------------------------------------------------
__global__ __launch_bounds__(256) void prep_a(
    const float* __restrict__ x0, const float* __restrict__ W0a,
    const float* __restrict__ b0a, const float* __restrict__ b0b,
    const float* __restrict__ W2, const float* __restrict__ W3,
    float* __restrict__ base, bf16_t* __restrict__ W2p, bf16_t* __restrict__ W3p)
{
  if (blockIdx.x < 2048) {
    int wid = (blockIdx.x << 2) + (threadIdx.x >> 6);   // 0..8191
    int L = threadIdx.x & 63;
    int m = wid >> 9, o = wid & 511;
    const float* wrow = W0a + ((size_t)(m*S0 + o) << 10);
    float acc = 0.f;
#pragma unroll
    for (int i = 0; i < 4; ++i) {
      f32x4 wv = *(const f32x4*)(wrow + i*256 + L*4);
      f32x4 xv = *(const f32x4*)(x0   + i*256 + L*4);
      acc += wv.x*xv.x + wv.y*xv.y + wv.z*xv.z + wv.w*xv.w;
    }
#pragma unroll
    for (int s = 32; s; s >>= 1) acc += __shfl_xor(acc, s, 64);
    if (L == 0) base[m*S0 + o] = acc + b0a[m*S0 + o] + b0b[m*S0 + o];
    return;
  }

  int T = (blockIdx.x - 2048) * 256 + threadIdx.x;  // 81920 total
  const float* src = nullptr;
  bf16_t* dst = nullptr;
  if (T < 65536) {                  // W2: 16m * 8ks * 8nt * 64L
    int L = T & 63, nt = (T >> 6) & 7, ks = (T >> 9) & 7, m = T >> 12;
    int n = nt*16 + (L & 15), k0 = ks*32 + ((L >> 4) & 3)*8;
    src = W2 + (size_t)(m*S2 + n)*S1 + k0;
    dst = W2p + (size_t)T*8;
  } else {                          // W3: 16m * 4ks * 1nt * 64L (N padded to 16)
    int T3 = T - 65536;
    int L = T3 & 63, ks = (T3 >> 6) & 3, m = T3 >> 8;
    int n = L & 15, k0 = ks*32 + ((L >> 4) & 3)*8;
    dst = W3p + (size_t)T3*8;
    if (n < 3) src = W3 + (size_t)(m*3 + n)*S2 + k0;
  }
  bf16x8 v;
  if (src) {
    f32x4 a = *(const f32x4*)src;
    f32x4 b = *(const f32x4*)(src + 4);
    v[0]=(bf16_t)a.x; v[1]=(bf16_t)a.y; v[2]=(bf16_t)a.z; v[3]=(bf16_t)a.w;
    v[4]=(bf16_t)b.x; v[5]=(bf16_t)b.y; v[6]=(bf16_t)b.z; v[7]=(bf16_t)b.w;
  } else {
#pragma unroll
    for (int j = 0; j < 8; ++j) v[j] = (bf16_t)0.f;
  }
  *(bf16x8*)dst = v;
}

// ---------------------------------------------------------------------------
// Launch 2: per-m channel classification over the full grid [-1,1]^2.
//   dead   : base + |wx| + |wy| <= 0  -> relu == 0 everywhere -> drop
//   linear : base - |wx| - |wy| >= 0  -> relu == identity     -> fold (rank-1)
//   active : the rest -> compacted (idx, basec, wxyc) for the MFMA path
// ---------------------------------------------------------------------------
__global__ __launch_bounds__(256) void classify_k(
    const float* __restrict__ base, const float* __restrict__ W0b,
    float* __restrict__ basec, float* __restrict__ wxyc,
    int* __restrict__ idx, int* __restrict__ lin,
    int* __restrict__ Kc, int* __restrict__ nlin, float* __restrict__ F)
{
  __shared__ int sc[512];
  const int m = blockIdx.x, t = threadIdx.x;
  float b[2], wx[2], wy[2]; int fa[2], fl[2];
#pragma unroll
  for (int h = 0; h < 2; ++h) {
    const int k = t + h*256;
    b[h]  = base[m*S0 + k];
    wx[h] = W0b[(m*S0 + k)*2];
    wy[h] = W0b[(m*S0 + k)*2 + 1];
    const float aw = fabsf(wx[h]) + fabsf(wy[h]);
    const int dead = (b[h] + aw) <= 0.f;
    fl[h] = (!dead) && ((b[h] - aw) >= 0.f);
    fa[h] = (!dead) && (!fl[h]);
    sc[k] = fa[h] | (fl[h] << 16);
  }
  __syncthreads();
  for (int off = 1; off < 512; off <<= 1) {
    int v0 = sc[t], v1 = sc[t+256];
    int u0 = (t >= off) ? sc[t-off] : 0;
    int u1 = (t+256 >= off) ? sc[t+256-off] : 0;
    __syncthreads();
    sc[t] = v0 + u0; sc[t+256] = v1 + u1;
    __syncthreads();
  }
  const int tot = sc[511];
  const int KcM = tot & 0xffff, nlM = tot >> 16;
#pragma unroll
  for (int h = 0; h < 2; ++h) {
    const int k = t + h*256;
    const int incl = sc[k];
    if (fa[h]) {
      const int p = (incl & 0xffff) - 1;
      idx[m*S0 + p] = k;
      basec[m*S0 + p] = b[h];
      wxyc[m*S0*2 + 2*p]     = wx[h];
      wxyc[m*S0*2 + 2*p + 1] = wy[h];
    } else if (fl[h]) {
      lin[m*S0 + ((incl >> 16) - 1)] = k;
    }
  }
  // zero tails (slots >= KcM are disjoint from the active writes above)
  for (int s = t; s < 512; s += 256) {
    if (s >= KcM) {
      idx[m*S0 + s] = 0;
      basec[m*S0 + s] = 0.f;
      wxyc[m*S0*2 + 2*s] = 0.f;
      wxyc[m*S0*2 + 2*s + 1] = 0.f;
    }
  }
  for (int i = t; i < 1024; i += 256) F[m*1024 + i] = 0.f;  // fold accumulators
  if (t == 0) { Kc[m] = KcM; nlin[m] = nlM; }
}

// ---------------------------------------------------------------------------
// Launch 3 (REWORKED): blocks [0,256): gather-pack W1 via LDS.
//   Round-10 post-mortem: the old gather did ~2M scattered 4B global reads
//   (random column per lane within each W1 row) — transaction/latency-bound,
//   the dominant part of the ~109 µs prep residual. Now: block = (m, nt)
//   loads its 16 W1 rows COALESCED into LDS (stride 516 f32: gather reads
//   (4*row+col)%32 -> 2-way, free), stages idx in LDS, then emits all 16 ks
//   fragment slices from cheap LDS gathers. Output bit-identical layout:
//   W1p[T*8], T = m*16384 + ks*1024 + nt*64 + L. Tails (kb+j >= Kc) zeroed.
// blocks [256,512): fold linear channels into F (16 k-slices, atomicAdd).
// ---------------------------------------------------------------------------
__global__ __launch_bounds__(256) void prep_b(
    const float* __restrict__ W1, const float* __restrict__ base,
    const float* __restrict__ W0b,
    const int* __restrict__ idx, const int* __restrict__ lin,
    const int* __restrict__ Kc, const int* __restrict__ nlin,
    bf16_t* __restrict__ W1p, float* __restrict__ F)
{
  if (blockIdx.x < 256) {
    __shared__ float sW1[16*516];   // 16 rows, stride 516 (516%32==4)
    __shared__ int   sIdx[512];
    const int b = blockIdx.x, m = b >> 4, nt = b & 15;
    const int t = threadIdx.x;
    const int KcM = Kc[m];
    sIdx[t]       = idx[m*S0 + t];
    sIdx[t + 256] = idx[m*S0 + t + 256];
    // coalesced row load: thread t -> row r = t>>4, cols (t&15)*4 + i*64
    const int r = t >> 4, cl = t & 15;
    const float* wrow = W1 + (size_t)(m*S1 + nt*16 + r)*S0;
#pragma unroll
    for (int i = 0; i < 8; ++i) {
      const int c = cl*4 + i*64;
      *(f32x4*)(&sW1[r*516 + c]) = *(const f32x4*)(wrow + c);
    }
    __syncthreads();
    // emit: thread t -> L = t&63, ks = (t>>6) + 4*kk
    const int L = t & 63, ksg = t >> 6;
    const int row = L & 15, q8 = ((L >> 4) & 3)*8;
    const float* srow = &sW1[row*516];
#pragma unroll
    for (int kk = 0; kk < 4; ++kk) {
      const int ks = ksg + kk*4;
      const int kb = ks*32 + q8;
      bf16x8 v;
#pragma unroll
      for (int j = 0; j < 8; ++j)
        v[j] = (kb + j < KcM) ? (bf16_t)srow[sIdx[kb + j]] : (bf16_t)0.f;
      *(bf16x8*)(W1p + ((size_t)(m*16 + ks)*1024 + nt*64 + L)*8) = v;
    }
  } else {
    const int b2 = blockIdx.x - 256;               // 0..255
    const int m = b2 >> 4, s = b2 & 15, n = threadIdx.x;
    const int nl = nlin[m];
    float a0 = 0.f, ax = 0.f, ay = 0.f;
    const float* wrow = W1 + (size_t)(m*S1 + n)*S0;
    for (int j = s; j < nl; j += 16) {
      const int k = lin[m*S0 + j];
      const float w = wrow[k];
      a0 = fmaf(w, base[m*S0 + k], a0);
      ax = fmaf(w, W0b[(m*S0 + k)*2], ax);
      ay = fmaf(w, W0b[(m*S0 + k)*2 + 1], ay);
    }
    float* fp = F + ((size_t)m*S1 + n)*4;
    atomicAdd(fp + 0, a0);
    atomicAdd(fp + 1, ax);
    atomicAdd(fp + 2, ay);
  }
}

// ---------------------------------------------------------------------------
// L1 K-loop (round-9 best, 85 µs): 128-row tile, static trip NKS, intra-wave
// pipeline with FULL FENCES (bare s_barrier is NOT a compiler memory fence).
// Per iteration:
//   {ds_read af0 rows 0-3 of buf cur} -> {Bn prefetch + GEN(ks+1) -> buf nxt}
//   -> lgkm(0) -> MFMA mt0-3 -> {ds_read af1 rows 4-7} -> lgkm(0) ->
//   MFMA mt4-7 -> barrier.
// WAR-safe: all reads of buf cur drained before the end barrier; buf cur is
// only rewritten by GEN(ks+2) after that barrier. Barriers = 1 + NKS.
// ---------------------------------------------------------------------------
template<int NKS>
__device__ __forceinline__ void l1_compute(
    const bf16_t* __restrict__ bp1, const float* __restrict__ bc,
    const float* __restrict__ wc, bf16_t* sStg,
    const int w, const int L, const int quad,
    const float yv, const float xg0, const float xg1, f32x4 (&acc1)[8][4])
{
  auto GEN = [&](int ks) {
    const int kk = ks*32 + quad*8;
    f32x4 cA  = *(const f32x4*)(bc + kk);
    f32x4 cB  = *(const f32x4*)(bc + kk + 4);
    f32x4 wv0 = *(const f32x4*)(wc + kk*2);
    f32x4 wv1 = *(const f32x4*)(wc + kk*2 + 4);
    f32x4 wv2 = *(const f32x4*)(wc + kk*2 + 8);
    f32x4 wv3 = *(const f32x4*)(wc + kk*2 + 12);
    float t[8], wx[8];
    t[0] = fmaf(wv0.y, yv, cA.x); wx[0] = wv0.x;
    t[1] = fmaf(wv0.w, yv, cA.y); wx[1] = wv0.z;
    t[2] = fmaf(wv1.y, yv, cA.z); wx[2] = wv1.x;
    t[3] = fmaf(wv1.w, yv, cA.w); wx[3] = wv1.z;
    t[4] = fmaf(wv2.y, yv, cB.x); wx[4] = wv2.x;
    t[5] = fmaf(wv2.w, yv, cB.y); wx[5] = wv2.z;
    t[6] = fmaf(wv3.y, yv, cB.z); wx[6] = wv3.x;
    t[7] = fmaf(wv3.w, yv, cB.w); wx[7] = wv3.z;
    bf16x8 g0, g1;
#pragma unroll
    for (int j = 0; j < 8; ++j) {
      g0[j] = (bf16_t)fmaxf(fmaf(wx[j], xg0, t[j]), 0.f);
      g1[j] = (bf16_t)fmaxf(fmaf(wx[j], xg1, t[j]), 0.f);
    }
    bf16_t* stg = sStg + (ks & 1)*4096;           // 2 x 8 KB buffers
    *(bf16x8*)(stg + (((2*w  ) << 6) + L)*8) = g0;
    *(bf16x8*)(stg + (((2*w+1) << 6) + L)*8) = g1;
  };

  bf16x8 Bc[4], Bn[4];
#pragma unroll
  for (int n = 0; n < 4; ++n) Bc[n] = *(const bf16x8*)(bp1 + (size_t)n*512);
  GEN(0);
  asm volatile("s_waitcnt lgkmcnt(0)" ::: "memory");
  asm volatile("s_barrier" ::: "memory");
  __builtin_amdgcn_sched_barrier(0);

#pragma unroll 2
  for (int ks = 0; ks < NKS; ++ks) {
    const bf16_t* stg = sStg + (ks & 1)*4096;
    bf16x8 af0[4];
#pragma unroll
    for (int mt = 0; mt < 4; ++mt)                 // issue rows 0-3 reads
      af0[mt] = *(const bf16x8*)(stg + ((mt << 6) + L)*8);
    if (ks + 1 < NKS) {                            // overlap: prefetch + gen
#pragma unroll
      for (int n = 0; n < 4; ++n)
        Bn[n] = *(const bf16x8*)(bp1 + (size_t)(ks+1)*8192 + (size_t)n*512);
      GEN(ks + 1);
    }
    asm volatile("s_waitcnt lgkmcnt(0)" ::: "memory");
    __builtin_amdgcn_sched_barrier(0);             // rule-18 fence
#pragma unroll
    for (int mt = 0; mt < 4; ++mt)
#pragma unroll
      for (int n = 0; n < 4; ++n)
        acc1[mt][n] = __builtin_amdgcn_mfma_f32_16x16x32_bf16(Bc[n], af0[mt], acc1[mt][n], 0, 0, 0);
    bf16x8 af1[4];
#pragma unroll
    for (int mt = 0; mt < 4; ++mt)                 // rows 4-7; latency under MFMA
      af1[mt] = *(const bf16x8*)(stg + (((mt + 4) << 6) + L)*8);
    asm volatile("s_waitcnt lgkmcnt(0)" ::: "memory");
    __builtin_amdgcn_sched_barrier(0);
#pragma unroll
    for (int mt = 0; mt < 4; ++mt)
#pragma unroll
      for (int n = 0; n < 4; ++n)
        acc1[mt+4][n] = __builtin_amdgcn_mfma_f32_16x16x32_bf16(Bc[n], af1[mt], acc1[mt+4][n], 0, 0, 0);
    asm volatile("s_barrier" ::: "memory");        // all waves' writes visible
    __builtin_amdgcn_sched_barrier(0);             // pin next-iter reads below
#pragma unroll
    for (int n = 0; n < 4; ++n) Bc[n] = Bn[n];
  }
}

// ---------------------------------------------------------------------------
// Fused MLP (round-9 best): 128-row supertile, WG = (m = bid>>7, st = bid&127).
// 4 waves, wave = col quarter; acc1[8][4] (128 AGPR), each B-frag feeds 8
// MFMAs. (256,2): 2 WGs/CU, 64 KB LDS. h1 [128][256] via T2 XOR swizzle.
// L1 compacted (nks = ceil(Kc/32) chunks, static trip via switch, pipelined);
// linear channels folded in the epilogue (F0 + Fx*x + Fy*y). MFMA (B,A)-
// swapped -> D = C^T. Frags: A/B row/col = lane&15, k = (lane>>4)*8+j;
// C/D: col = lane&15, row = quad*4+p.
// ---------------------------------------------------------------------------
__global__ __launch_bounds__(256, 2) void fused_mlp_k(
    const float* __restrict__ basec, const float* __restrict__ wxyc,
    const float* __restrict__ F, const int* __restrict__ Kc,
    const bf16_t* __restrict__ W1p, const bf16_t* __restrict__ W2p,
    const bf16_t* __restrict__ W3p,
    const float* __restrict__ b1, const float* __restrict__ b2,
    const float* __restrict__ b3, float* __restrict__ out)
{
  __shared__ __align__(16) bf16_t sLDS[128*256];  // 64 KB: L1 staging (16 KB
                                                  // head), h1 swizzled, h2

  const int bid = blockIdx.x;
  const int m   = bid >> 7;             // m-major: L2-resident weights
  const int st  = bid & 127;            // grid row-line (y index)

  const int tid  = threadIdx.x;
  const int w    = tid >> 6, L = tid & 63;
  const int quad = L >> 4, lrow = L & 15;

  const float step = 2.0f / 127.0f;
  const float yv  = -1.0f + (float)st * step;
  const float xv0 = -1.0f + (float)lrow * step;          // x at row=lrow
  const float xg0 = xv0 + (float)((2*w  )*16)*step;      // gen block 2w
  const float xg1 = xv0 + (float)((2*w+1)*16)*step;      // gen block 2w+1

  const float* bc = basec + m*S0;
  const float* wc = wxyc + m*(S0*2);
  const int nks = (Kc[m] + 31) >> 5;    // compacted K-chunks (~10 of 16)

  f32x4 zero = {0.f, 0.f, 0.f, 0.f};
  f32x4 acc1[8][4];
#pragma unroll
  for (int a = 0; a < 8; ++a)
#pragma unroll
    for (int b = 0; b < 4; ++b) acc1[a][b] = zero;

  // ---------------- Layer 1: static-trip compacted pipelined K-loop ----------------
  const bf16_t* bp1 = W1p + (((size_t)(m*16)*16 + w*4)*64 + L)*8;
#define L1_CASE(NN) case NN: l1_compute<NN>(bp1, bc, wc, sLDS, w, L, quad, yv, xg0, xg1, acc1); break;
  switch (nks) {
    L1_CASE(16) L1_CASE(15) L1_CASE(14) L1_CASE(13)
    L1_CASE(12) L1_CASE(11) L1_CASE(10) L1_CASE(9)
    L1_CASE(8)  L1_CASE(7)  L1_CASE(6)  L1_CASE(5)
    L1_CASE(4)  L1_CASE(3)  L1_CASE(2)  L1_CASE(1)
    default: break;   // nks == 0: all channels dead/linear, acc stays 0
  }
#undef L1_CASE
  __syncthreads();   // staging reads done before epilogue overwrites sLDS

  // L1 epilogue: bias + linear fold (F0 + Fx*x + Fy*y), relu, D^T ->
  // thread holds 4 contiguous cols -> 8B swizzled stores
#pragma unroll
  for (int nb = 0; nb < 4; ++nb) {
    const int col = w*64 + nb*16 + quad*4;
    f32x4 bb = *(const f32x4*)(b1 + m*S1 + col);
    float cterm[4], fx[4];
#pragma unroll
    for (int p = 0; p < 4; ++p) {
      f32x4 Fv = *(const f32x4*)(F + ((size_t)m*S1 + col + p)*4);
      cterm[p] = fmaf(Fv.z, yv, bb[p] + Fv.x);   // b1 + F0 + Fy*y
      fx[p] = Fv.y;
    }
#pragma unroll
    for (int mt = 0; mt < 8; ++mt) {
      const int row = mt*16 + lrow;
      const float xr = xv0 + (float)(mt*16)*step;
      bf16x4 v;
#pragma unroll
      for (int p = 0; p < 4; ++p)
        v[p] = (bf16_t)fmaxf(acc1[mt][nb][p] + fmaf(fx[p], xr, cterm[p]), 0.f);
      st_h1(sLDS, row, col, v);
    }
  }
  __syncthreads();

  // ---------------- Layer 2: K=256, 8 chunks, 16 MFMAs each ----------------
  f32x4 acc2[8][2];
#pragma unroll
  for (int a = 0; a < 8; ++a) { acc2[a][0] = zero; acc2[a][1] = zero; }
  const bf16_t* bp2 = W2p + (((size_t)(m*8)*8 + w*2)*64 + L)*8;
#pragma unroll 2
  for (int ks = 0; ks < 8; ++ks) {
    const int k2 = ks*32 + quad*8;
    bf16x8 b0f = *(const bf16x8*)(bp2 + (size_t)ks*4096);
    bf16x8 b1f = *(const bf16x8*)(bp2 + (size_t)ks*4096 + 512);
#pragma unroll
    for (int mt = 0; mt < 8; ++mt) {
      bf16x8 af = ld_h1(sLDS, mt*16 + lrow, k2);
      acc2[mt][0] = __builtin_amdgcn_mfma_f32_16x16x32_bf16(b0f, af, acc2[mt][0], 0, 0, 0);
      acc2[mt][1] = __builtin_amdgcn_mfma_f32_16x16x32_bf16(b1f, af, acc2[mt][1], 0, 0, 0);
    }
  }
  __syncthreads();   // all h1 reads done before aliased h2 writes

  // L2 epilogue: h2 -> sH2 [128][136], packed b64 stores
  bf16_t* sH2 = sLDS;
#pragma unroll
  for (int nb = 0; nb < 2; ++nb) {
    const int col = w*32 + nb*16 + quad*4;
    f32x4 bb = *(const f32x4*)(b2 + m*S2 + col);
#pragma unroll
    for (int mt = 0; mt < 8; ++mt) {
      const int row = mt*16 + lrow;
      bf16x4 v;
#pragma unroll
      for (int p = 0; p < 4; ++p)
        v[p] = (bf16_t)fmaxf(acc2[mt][nb][p] + bb[p], 0.f);
      *(bf16x4*)(&sH2[row*136 + col]) = v;
    }
  }
  __syncthreads();

  // ---------------- Layer 3: K=128; wave w does row-blocks w and w+4 ----------------
  f32x4 acc3[2] = {zero, zero};
#pragma unroll
  for (int ks = 0; ks < 4; ++ks) {
    bf16x8 bfr = *(const bf16x8*)(W3p + (((size_t)m*4 + ks)*64 + L)*8);
    bf16x8 af0 = *(const bf16x8*)(&sH2[((w  )*16 + lrow)*136 + ks*32 + quad*8]);
    bf16x8 af1 = *(const bf16x8*)(&sH2[((w+4)*16 + lrow)*136 + ks*32 + quad*8]);
    acc3[0] = __builtin_amdgcn_mfma_f32_16x16x32_bf16(bfr, af0, acc3[0], 0, 0, 0);
    acc3[1] = __builtin_amdgcn_mfma_f32_16x16x32_bf16(bfr, af1, acc3[1], 0, 0, 0);
  }
  if (quad == 0) {   // thread holds channels p=0..3 for its grid rows
#pragma unroll
    for (int ri = 0; ri < 2; ++ri) {
      const int rb = w + ri*4;
      const size_t o = ((size_t)m*GPTS + (size_t)st*128 + rb*16 + lrow)*3;
      out[o + 0] = tanh_fast(acc3[ri][0] + b3[m*3 + 0]);
      out[o + 1] = tanh_fast(acc3[ri][1] + b3[m*3 + 1]);
      out[o + 2] = tanh_fast(acc3[ri][2] + b3[m*3 + 2]);
    }
  }
}

// ---------------------------------------------------------------------------
extern "C" void kernel_launch(void* const* d_in, const int* in_sizes, int n_in,
                              void* d_out, int out_size, void* d_ws, size_t ws_size,
                              hipStream_t stream) {
  const float* x0  = (const float*)d_in[0];
  const float* W0a = (const float*)d_in[1];
  const float* b0a = (const float*)d_in[2];
  const float* W0b = (const float*)d_in[3];
  const float* b0b = (const float*)d_in[4];
  const float* W1  = (const float*)d_in[5];
  const float* b1  = (const float*)d_in[6];
  const float* W2  = (const float*)d_in[7];
  const float* b2  = (const float*)d_in[8];
  const float* W3  = (const float*)d_in[9];
  const float* b3  = (const float*)d_in[10];

  char* ws = (char*)d_ws;
  float*  base  = (float*)(ws + WS_BASE);
  bf16_t* W1p   = (bf16_t*)(ws + WS_W1P);
  bf16_t* W2p   = (bf16_t*)(ws + WS_W2P);
  bf16_t* W3p   = (bf16_t*)(ws + WS_W3P);
  float*  basec = (float*)(ws + WS_BASEC);
  float*  wxyc  = (float*)(ws + WS_WXYC);
  int*    idx   = (int*)(ws + WS_IDX);
  int*    lin   = (int*)(ws + WS_LIN);
  float*  F     = (float*)(ws + WS_F);
  int*    Kc    = (int*)(ws + WS_CNT);
  int*    nlin  = (int*)(ws + WS_CNT + 64);
  float*  out   = (float*)d_out;

  prep_a<<<2368, 256, 0, stream>>>(x0, W0a, b0a, b0b, W2, W3, base, W2p, W3p);
  classify_k<<<16, 256, 0, stream>>>(base, W0b, basec, wxyc, idx, lin, Kc, nlin, F);
  prep_b<<<512, 256, 0, stream>>>(W1, base, W0b, idx, lin, Kc, nlin, W1p, F);
  fused_mlp_k<<<2048, 256, 0, stream>>>(basec, wxyc, F, Kc, W1p, W2p, W3p, b1, b2, b3, out);
}

// Round 13
// 180.308 us; speedup vs baseline: 1.0888x; 1.0426x over previous
//
#include <hip/hip_runtime.h>
#include <hip/hip_bf16.h>
#include <cstdint>

typedef __bf16 bf16_t;
typedef bf16_t bf16x8 __attribute__((ext_vector_type(8)));
typedef bf16_t bf16x4 __attribute__((ext_vector_type(4)));
typedef float  f32x4  __attribute__((ext_vector_type(4)));

#define S0 512
#define S1 256
#define S2 128
#define NGRID 128
#define GPTS (NGRID*NGRID)   // 16384

// workspace layout (bytes)
#define WS_BASE  0u          // 16*512 f32            = 32 KB
#define WS_W1P   32768u      // 262144*8 bf16         = 4 MB
#define WS_W2P   4227072u    // 65536*8 bf16          = 1 MB
#define WS_W3P   5275648u    // 4096*8 bf16           = 64 KB
#define WS_BASEC 5341184u    // 16*512 f32 compacted  = 32 KB
#define WS_WXYC  5373952u    // 16*512*2 f32          = 64 KB
#define WS_IDX   5439488u    // 16*512 int            = 32 KB
#define WS_LIN   5472256u    // 16*512 int            = 32 KB
#define WS_F     5505024u    // 16*256*4 f32          = 64 KB
#define WS_CNT   5570560u    // Kc[16] + nlin[16]

__device__ __forceinline__ float tanh_fast(float x) {
  float e = __builtin_amdgcn_exp2f(x * 2.88539008f);   // 2*log2(e)
  return fmaf(-2.0f, __builtin_amdgcn_rcpf(e + 1.0f), 1.0f);
}

// h1 LDS tile [128 rows][256 cols] bf16, 64 KB exactly (no pad possible) ->
// T2 XOR swizzle keeps stride-512B column reads 2-way-conflict-free:
//   phys_byte(row,col) = row*512 + ((col*2) ^ ((row&7)<<4))
__device__ __forceinline__ bf16x8 ld_h1(const bf16_t* s, int row, int colk) {
  const int byte = row*512 + (((colk*2) ^ ((row & 7) << 4)));
  return *(const bf16x8*)((const char*)s + byte);
}
__device__ __forceinline__ void st_h1(bf16_t* s, int row, int col, bf16x4 v) {
  const int byte = row*512 + (((col*2) ^ ((row & 7) << 4)));
  *(bf16x4*)((char*)s + byte) = v;
}

// ---------------------------------------------------------------------------
// Launch 1: blocks [0,2048): base[m][o] = W0a·x0 + b0a + b0b  (fp32)
//           blocks [2048,2368): pack W2/W3 into bf16 MFMA B-frag order
// ---------------------------------------------------------------------------
__global__ __launch_bounds__(256) void prep_a(
    const float* __restrict__ x0, const float* __restrict__ W0a,
    const float* __restrict__ b0a, const float* __restrict__ b0b,
    const float* __restrict__ W2, const float* __restrict__ W3,
    float* __restrict__ base, bf16_t* __restrict__ W2p, bf16_t* __restrict__ W3p)
{
  if (blockIdx.x < 2048) {
    int wid = (blockIdx.x << 2) + (threadIdx.x >> 6);   // 0..8191
    int L = threadIdx.x & 63;
    int m = wid >> 9, o = wid & 511;
    const float* wrow = W0a + ((size_t)(m*S0 + o) << 10);
    float acc = 0.f;
#pragma unroll
    for (int i = 0; i < 4; ++i) {
      f32x4 wv = *(const f32x4*)(wrow + i*256 + L*4);
      f32x4 xv = *(const f32x4*)(x0   + i*256 + L*4);
      acc += wv.x*xv.x + wv.y*xv.y + wv.z*xv.z + wv.w*xv.w;
    }
#pragma unroll
    for (int s = 32; s; s >>= 1) acc += __shfl_xor(acc, s, 64);
    if (L == 0) base[m*S0 + o] = acc + b0a[m*S0 + o] + b0b[m*S0 + o];
    return;
  }

  int T = (blockIdx.x - 2048) * 256 + threadIdx.x;  // 81920 total
  const float* src = nullptr;
  bf16_t* dst = nullptr;
  if (T < 65536) {                  // W2: 16m * 8ks * 8nt * 64L
    int L = T & 63, nt = (T >> 6) & 7, ks = (T >> 9) & 7, m = T >> 12;
    int n = nt*16 + (L & 15), k0 = ks*32 + ((L >> 4) & 3)*8;
    src = W2 + (size_t)(m*S2 + n)*S1 + k0;
    dst = W2p + (size_t)T*8;
  } else {                          // W3: 16m * 4ks * 1nt * 64L (N padded to 16)
    int T3 = T - 65536;
    int L = T3 & 63, ks = (T3 >> 6) & 3, m = T3 >> 8;
    int n = L & 15, k0 = ks*32 + ((L >> 4) & 3)*8;
    dst = W3p + (size_t)T3*8;
    if (n < 3) src = W3 + (size_t)(m*3 + n)*S2 + k0;
  }
  bf16x8 v;
  if (src) {
    f32x4 a = *(const f32x4*)src;
    f32x4 b = *(const f32x4*)(src + 4);
    v[0]=(bf16_t)a.x; v[1]=(bf16_t)a.y; v[2]=(bf16_t)a.z; v[3]=(bf16_t)a.w;
    v[4]=(bf16_t)b.x; v[5]=(bf16_t)b.y; v[6]=(bf16_t)b.z; v[7]=(bf16_t)b.w;
  } else {
#pragma unroll
    for (int j = 0; j < 8; ++j) v[j] = (bf16_t)0.f;
  }
  *(bf16x8*)dst = v;
}

// ---------------------------------------------------------------------------
// Launch 2: per-m channel classification over the full grid [-1,1]^2.
//   dead   : base + |wx| + |wy| <= 0  -> relu == 0 everywhere -> drop
//   linear : base - |wx| - |wy| >= 0  -> relu == identity     -> fold (rank-1)
//   active : the rest -> compacted (idx, basec, wxyc) for the MFMA path
// NOTE: two attempts to fold this into prep_b via ballot-scan (r8, r12)
// failed with identical absmax 0.3725586 — defect in that merge never
// located; the Hillis-Steele version below is the proven path. Do not
// retire it without a verified replacement.
// ---------------------------------------------------------------------------
__global__ __launch_bounds__(256) void classify_k(
    const float* __restrict__ base, const float* __restrict__ W0b,
    float* __restrict__ basec, float* __restrict__ wxyc,
    int* __restrict__ idx, int* __restrict__ lin,
    int* __restrict__ Kc, int* __restrict__ nlin, float* __restrict__ F)
{
  __shared__ int sc[512];
  const int m = blockIdx.x, t = threadIdx.x;
  float b[2], wx[2], wy[2]; int fa[2], fl[2];
#pragma unroll
  for (int h = 0; h < 2; ++h) {
    const int k = t + h*256;
    b[h]  = base[m*S0 + k];
    wx[h] = W0b[(m*S0 + k)*2];
    wy[h] = W0b[(m*S0 + k)*2 + 1];
    const float aw = fabsf(wx[h]) + fabsf(wy[h]);
    const int dead = (b[h] + aw) <= 0.f;
    fl[h] = (!dead) && ((b[h] - aw) >= 0.f);
    fa[h] = (!dead) && (!fl[h]);
    sc[k] = fa[h] | (fl[h] << 16);
  }
  __syncthreads();
  for (int off = 1; off < 512; off <<= 1) {
    int v0 = sc[t], v1 = sc[t+256];
    int u0 = (t >= off) ? sc[t-off] : 0;
    int u1 = (t+256 >= off) ? sc[t+256-off] : 0;
    __syncthreads();
    sc[t] = v0 + u0; sc[t+256] = v1 + u1;
    __syncthreads();
  }
  const int tot = sc[511];
  const int KcM = tot & 0xffff, nlM = tot >> 16;
#pragma unroll
  for (int h = 0; h < 2; ++h) {
    const int k = t + h*256;
    const int incl = sc[k];
    if (fa[h]) {
      const int p = (incl & 0xffff) - 1;
      idx[m*S0 + p] = k;
      basec[m*S0 + p] = b[h];
      wxyc[m*S0*2 + 2*p]     = wx[h];
      wxyc[m*S0*2 + 2*p + 1] = wy[h];
    } else if (fl[h]) {
      lin[m*S0 + ((incl >> 16) - 1)] = k;
    }
  }
  // zero tails (slots >= KcM are disjoint from the active writes above)
  for (int s = t; s < 512; s += 256) {
    if (s >= KcM) {
      idx[m*S0 + s] = 0;
      basec[m*S0 + s] = 0.f;
      wxyc[m*S0*2 + 2*s] = 0.f;
      wxyc[m*S0*2 + 2*s + 1] = 0.f;
    }
  }
  for (int i = t; i < 1024; i += 256) F[m*1024 + i] = 0.f;  // fold accumulators
  if (t == 0) { Kc[m] = KcM; nlin[m] = nlM; }
}

// ---------------------------------------------------------------------------
// Launch 3: blocks [0,256): gather-pack W1 via LDS. Block = (m, nt) loads its
//   16 W1 rows COALESCED into LDS (stride 516 f32), stages idx in LDS, then
//   emits all 16 ks fragment slices from LDS gathers. Tails zeroed.
// blocks [256,512): fold linear channels into F (16 k-slices, atomicAdd).
// ---------------------------------------------------------------------------
__global__ __launch_bounds__(256) void prep_b(
    const float* __restrict__ W1, const float* __restrict__ base,
    const float* __restrict__ W0b,
    const int* __restrict__ idx, const int* __restrict__ lin,
    const int* __restrict__ Kc, const int* __restrict__ nlin,
    bf16_t* __restrict__ W1p, float* __restrict__ F)
{
  if (blockIdx.x < 256) {
    __shared__ float sW1[16*516];   // 16 rows, stride 516 (516%32==4)
    __shared__ int   sIdx[512];
    const int b = blockIdx.x, m = b >> 4, nt = b & 15;
    const int t = threadIdx.x;
    const int KcM = Kc[m];
    sIdx[t]       = idx[m*S0 + t];
    sIdx[t + 256] = idx[m*S0 + t + 256];
    // coalesced row load: thread t -> row r = t>>4, cols (t&15)*4 + i*64
    const int r = t >> 4, cl = t & 15;
    const float* wrow = W1 + (size_t)(m*S1 + nt*16 + r)*S0;
#pragma unroll
    for (int i = 0; i < 8; ++i) {
      const int c = cl*4 + i*64;
      *(f32x4*)(&sW1[r*516 + c]) = *(const f32x4*)(wrow + c);
    }
    __syncthreads();
    // emit: thread t -> L = t&63, ks = (t>>6) + 4*kk
    const int L = t & 63, ksg = t >> 6;
    const int row = L & 15, q8 = ((L >> 4) & 3)*8;
    const float* srow = &sW1[row*516];
#pragma unroll
    for (int kk = 0; kk < 4; ++kk) {
      const int ks = ksg + kk*4;
      const int kb = ks*32 + q8;
      bf16x8 v;
#pragma unroll
      for (int j = 0; j < 8; ++j)
        v[j] = (kb + j < KcM) ? (bf16_t)srow[sIdx[kb + j]] : (bf16_t)0.f;
      *(bf16x8*)(W1p + ((size_t)(m*16 + ks)*1024 + nt*64 + L)*8) = v;
    }
  } else {
    const int b2 = blockIdx.x - 256;               // 0..255
    const int m = b2 >> 4, s = b2 & 15, n = threadIdx.x;
    const int nl = nlin[m];
    float a0 = 0.f, ax = 0.f, ay = 0.f;
    const float* wrow = W1 + (size_t)(m*S1 + n)*S0;
    for (int j = s; j < nl; j += 16) {
      const int k = lin[m*S0 + j];
      const float w = wrow[k];
      a0 = fmaf(w, base[m*S0 + k], a0);
      ax = fmaf(w, W0b[(m*S0 + k)*2], ax);
      ay = fmaf(w, W0b[(m*S0 + k)*2 + 1], ay);
    }
    float* fp = F + ((size_t)m*S1 + n)*4;
    atomicAdd(fp + 0, a0);
    atomicAdd(fp + 1, ax);
    atomicAdd(fp + 2, ay);
  }
}

// ---------------------------------------------------------------------------
// L1 K-loop (round-9 best, 85 µs): 128-row tile, static trip NKS, intra-wave
// pipeline with FULL FENCES (bare s_barrier is NOT a compiler memory fence).
// Per iteration:
//   {ds_read af0 rows 0-3 of buf cur} -> {Bn prefetch + GEN(ks+1) -> buf nxt}
//   -> lgkm(0) -> MFMA mt0-3 -> {ds_read af1 rows 4-7} -> lgkm(0) ->
//   MFMA mt4-7 -> barrier.
// WAR-safe: all reads of buf cur drained before the end barrier; buf cur is
// only rewritten by GEN(ks+2) after that barrier. Barriers = 1 + NKS.
// ---------------------------------------------------------------------------
template<int NKS>
__device__ __forceinline__ void l1_compute(
    const bf16_t* __restrict__ bp1, const float* __restrict__ bc,
    const float* __restrict__ wc, bf16_t* sStg,
    const int w, const int L, const int quad,
    const float yv, const float xg0, const float xg1, f32x4 (&acc1)[8][4])
{
  auto GEN = [&](int ks) {
    const int kk = ks*32 + quad*8;
    f32x4 cA  = *(const f32x4*)(bc + kk);
    f32x4 cB  = *(const f32x4*)(bc + kk + 4);
    f32x4 wv0 = *(const f32x4*)(wc + kk*2);
    f32x4 wv1 = *(const f32x4*)(wc + kk*2 + 4);
    f32x4 wv2 = *(const f32x4*)(wc + kk*2 + 8);
    f32x4 wv3 = *(const f32x4*)(wc + kk*2 + 12);
    float t[8], wx[8];
    t[0] = fmaf(wv0.y, yv, cA.x); wx[0] = wv0.x;
    t[1] = fmaf(wv0.w, yv, cA.y); wx[1] = wv0.z;
    t[2] = fmaf(wv1.y, yv, cA.z); wx[2] = wv1.x;
    t[3] = fmaf(wv1.w, yv, cA.w); wx[3] = wv1.z;
    t[4] = fmaf(wv2.y, yv, cB.x); wx[4] = wv2.x;
    t[5] = fmaf(wv2.w, yv, cB.y); wx[5] = wv2.z;
    t[6] = fmaf(wv3.y, yv, cB.z); wx[6] = wv3.x;
    t[7] = fmaf(wv3.w, yv, cB.w); wx[7] = wv3.z;
    bf16x8 g0, g1;
#pragma unroll
    for (int j = 0; j < 8; ++j) {
      g0[j] = (bf16_t)fmaxf(fmaf(wx[j], xg0, t[j]), 0.f);
      g1[j] = (bf16_t)fmaxf(fmaf(wx[j], xg1, t[j]), 0.f);
    }
    bf16_t* stg = sStg + (ks & 1)*4096;           // 2 x 8 KB buffers
    *(bf16x8*)(stg + (((2*w  ) << 6) + L)*8) = g0;
    *(bf16x8*)(stg + (((2*w+1) << 6) + L)*8) = g1;
  };

  bf16x8 Bc[4], Bn[4];
#pragma unroll
  for (int n = 0; n < 4; ++n) Bc[n] = *(const bf16x8*)(bp1 + (size_t)n*512);
  GEN(0);
  asm volatile("s_waitcnt lgkmcnt(0)" ::: "memory");
  asm volatile("s_barrier" ::: "memory");
  __builtin_amdgcn_sched_barrier(0);

#pragma unroll 2
  for (int ks = 0; ks < NKS; ++ks) {
    const bf16_t* stg = sStg + (ks & 1)*4096;
    bf16x8 af0[4];
#pragma unroll
    for (int mt = 0; mt < 4; ++mt)                 // issue rows 0-3 reads
      af0[mt] = *(const bf16x8*)(stg + ((mt << 6) + L)*8);
    if (ks + 1 < NKS) {                            // overlap: prefetch + gen
#pragma unroll
      for (int n = 0; n < 4; ++n)
        Bn[n] = *(const bf16x8*)(bp1 + (size_t)(ks+1)*8192 + (size_t)n*512);
      GEN(ks + 1);
    }
    asm volatile("s_waitcnt lgkmcnt(0)" ::: "memory");
    __builtin_amdgcn_sched_barrier(0);             // rule-18 fence
#pragma unroll
    for (int mt = 0; mt < 4; ++mt)
#pragma unroll
      for (int n = 0; n < 4; ++n)
        acc1[mt][n] = __builtin_amdgcn_mfma_f32_16x16x32_bf16(Bc[n], af0[mt], acc1[mt][n], 0, 0, 0);
    bf16x8 af1[4];
#pragma unroll
    for (int mt = 0; mt < 4; ++mt)                 // rows 4-7; latency under MFMA
      af1[mt] = *(const bf16x8*)(stg + (((mt + 4) << 6) + L)*8);
    asm volatile("s_waitcnt lgkmcnt(0)" ::: "memory");
    __builtin_amdgcn_sched_barrier(0);
#pragma unroll
    for (int mt = 0; mt < 4; ++mt)
#pragma unroll
      for (int n = 0; n < 4; ++n)
        acc1[mt+4][n] = __builtin_amdgcn_mfma_f32_16x16x32_bf16(Bc[n], af1[mt], acc1[mt+4][n], 0, 0, 0);
    asm volatile("s_barrier" ::: "memory");        // all waves' writes visible
    __builtin_amdgcn_sched_barrier(0);             // pin next-iter reads below
#pragma unroll
    for (int n = 0; n < 4; ++n) Bc[n] = Bn[n];
  }
}

// ---------------------------------------------------------------------------
// Fused MLP (round-9/11 best): 128-row supertile, WG = (m, st) via an
// XCD-AWARE BIJECTIVE SWIZZLE (T1): logical bid = (hw%8)*256 + hw/8.
// 2048 = 8*256 -> bijective. Each XCD owns a contiguous 256-block chunk =
// exactly 2 m's -> that XCD's L2 holds only ~0.6 MB of packed weights
// (vs all 16 m's ~5 MB with round-robin) -> W1p/W2p firmly L2-resident.
// 4 waves, wave = col quarter; acc1[8][4] (128 AGPR), each B-frag feeds 8
// MFMAs. (256,2): 2 WGs/CU, 64 KB LDS. h1 [128][256] via T2 XOR swizzle.
// L1 compacted (nks = ceil(Kc/32), static trip via switch, pipelined);
// linear channels folded in the epilogue (F0 + Fx*x + Fy*y). MFMA (B,A)-
// swapped -> D = C^T. Frags: A/B row/col = lane&15, k = (lane>>4)*8+j;
// C/D: col = lane&15, row = quad*4+p.
// ---------------------------------------------------------------------------
__global__ __launch_bounds__(256, 2) void fused_mlp_k(
    const float* __restrict__ basec, const float* __restrict__ wxyc,
    const float* __restrict__ F, const int* __restrict__ Kc,
    const bf16_t* __restrict__ W1p, const bf16_t* __restrict__ W2p,
    const bf16_t* __restrict__ W3p,
    const float* __restrict__ b1, const float* __restrict__ b2,
    const float* __restrict__ b3, float* __restrict__ out)
{
  __shared__ __align__(16) bf16_t sLDS[128*256];  // 64 KB: L1 staging (16 KB
                                                  // head), h1 swizzled, h2

  const int bid0 = blockIdx.x;
  const int bid  = ((bid0 & 7) << 8) | (bid0 >> 3);  // T1 XCD swizzle, bijective
  const int m    = bid >> 7;            // m-major within each XCD chunk
  const int st   = bid & 127;           // grid row-line (y index)

  const int tid  = threadIdx.x;
  const int w    = tid >> 6, L = tid & 63;
  const int quad = L >> 4, lrow = L & 15;

  const float step = 2.0f / 127.0f;
  const float yv  = -1.0f + (float)st * step;
  const float xv0 = -1.0f + (float)lrow * step;          // x at row=lrow
  const float xg0 = xv0 + (float)((2*w  )*16)*step;      // gen block 2w
  const float xg1 = xv0 + (float)((2*w+1)*16)*step;      // gen block 2w+1

  const float* bc = basec + m*S0;
  const float* wc = wxyc + m*(S0*2);
  const int nks = (Kc[m] + 31) >> 5;    // compacted K-chunks (~10 of 16)

  f32x4 zero = {0.f, 0.f, 0.f, 0.f};
  f32x4 acc1[8][4];
#pragma unroll
  for (int a = 0; a < 8; ++a)
#pragma unroll
    for (int b = 0; b < 4; ++b) acc1[a][b] = zero;

  // ---------------- Layer 1: static-trip compacted pipelined K-loop ----------------
  const bf16_t* bp1 = W1p + (((size_t)(m*16)*16 + w*4)*64 + L)*8;
#define L1_CASE(NN) case NN: l1_compute<NN>(bp1, bc, wc, sLDS, w, L, quad, yv, xg0, xg1, acc1); break;
  switch (nks) {
    L1_CASE(16) L1_CASE(15) L1_CASE(14) L1_CASE(13)
    L1_CASE(12) L1_CASE(11) L1_CASE(10) L1_CASE(9)
    L1_CASE(8)  L1_CASE(7)  L1_CASE(6)  L1_CASE(5)
    L1_CASE(4)  L1_CASE(3)  L1_CASE(2)  L1_CASE(1)
    default: break;   // nks == 0: all channels dead/linear, acc stays 0
  }
#undef L1_CASE
  __syncthreads();   // staging reads done before epilogue overwrites sLDS

  // L1 epilogue: bias + linear fold (F0 + Fx*x + Fy*y), relu, D^T ->
  // thread holds 4 contiguous cols -> 8B swizzled stores
#pragma unroll
  for (int nb = 0; nb < 4; ++nb) {
    const int col = w*64 + nb*16 + quad*4;
    f32x4 bb = *(const f32x4*)(b1 + m*S1 + col);
    float cterm[4], fx[4];
#pragma unroll
    for (int p = 0; p < 4; ++p) {
      f32x4 Fv = *(const f32x4*)(F + ((size_t)m*S1 + col + p)*4);
      cterm[p] = fmaf(Fv.z, yv, bb[p] + Fv.x);   // b1 + F0 + Fy*y
      fx[p] = Fv.y;
    }
#pragma unroll
    for (int mt = 0; mt < 8; ++mt) {
      const int row = mt*16 + lrow;
      const float xr = xv0 + (float)(mt*16)*step;
      bf16x4 v;
#pragma unroll
      for (int p = 0; p < 4; ++p)
        v[p] = (bf16_t)fmaxf(acc1[mt][nb][p] + fmaf(fx[p], xr, cterm[p]), 0.f);
      st_h1(sLDS, row, col, v);
    }
  }
  __syncthreads();

  // ---------------- Layer 2: K=256, 8 chunks, 16 MFMAs each ----------------
  f32x4 acc2[8][2];
#pragma unroll
  for (int a = 0; a < 8; ++a) { acc2[a][0] = zero; acc2[a][1] = zero; }
  const bf16_t* bp2 = W2p + (((size_t)(m*8)*8 + w*2)*64 + L)*8;
#pragma unroll 2
  for (int ks = 0; ks < 8; ++ks) {
    const int k2 = ks*32 + quad*8;
    bf16x8 b0f = *(const bf16x8*)(bp2 + (size_t)ks*4096);
    bf16x8 b1f = *(const bf16x8*)(bp2 + (size_t)ks*4096 + 512);
#pragma unroll
    for (int mt = 0; mt < 8; ++mt) {
      bf16x8 af = ld_h1(sLDS, mt*16 + lrow, k2);
      acc2[mt][0] = __builtin_amdgcn_mfma_f32_16x16x32_bf16(b0f, af, acc2[mt][0], 0, 0, 0);
      acc2[mt][1] = __builtin_amdgcn_mfma_f32_16x16x32_bf16(b1f, af, acc2[mt][1], 0, 0, 0);
    }
  }
  __syncthreads();   // all h1 reads done before aliased h2 writes

  // L2 epilogue: h2 -> sH2 [128][136], packed b64 stores
  bf16_t* sH2 = sLDS;
#pragma unroll
  for (int nb = 0; nb < 2; ++nb) {
    const int col = w*32 + nb*16 + quad*4;
    f32x4 bb = *(const f32x4*)(b2 + m*S2 + col);
#pragma unroll
    for (int mt = 0; mt < 8; ++mt) {
      const int row = mt*16 + lrow;
      bf16x4 v;
#pragma unroll
      for (int p = 0; p < 4; ++p)
        v[p] = (bf16_t)fmaxf(acc2[mt][nb][p] + bb[p], 0.f);
      *(bf16x4*)(&sH2[row*136 + col]) = v;
    }
  }
  __syncthreads();

  // ---------------- Layer 3: K=128; wave w does row-blocks w and w+4 ----------------
  f32x4 acc3[2] = {zero, zero};
#pragma unroll
  for (int ks = 0; ks < 4; ++ks) {
    bf16x8 bfr = *(const bf16x8*)(W3p + (((size_t)m*4 + ks)*64 + L)*8);
    bf16x8 af0 = *(const bf16x8*)(&sH2[((w  )*16 + lrow)*136 + ks*32 + quad*8]);
    bf16x8 af1 = *(const bf16x8*)(&sH2[((w+4)*16 + lrow)*136 + ks*32 + quad*8]);
    acc3[0] = __builtin_amdgcn_mfma_f32_16x16x32_bf16(bfr, af0, acc3[0], 0, 0, 0);
    acc3[1] = __builtin_amdgcn_mfma_f32_16x16x32_bf16(bfr, af1, acc3[1], 0, 0, 0);
  }
  if (quad == 0) {   // thread holds channels p=0..3 for its grid rows
#pragma unroll
    for (int ri = 0; ri < 2; ++ri) {
      const int rb = w + ri*4;
      const size_t o = ((size_t)m*GPTS + (size_t)st*128 + rb*16 + lrow)*3;
      out[o + 0] = tanh_fast(acc3[ri][0] + b3[m*3 + 0]);
      out[o + 1] = tanh_fast(acc3[ri][1] + b3[m*3 + 1]);
      out[o + 2] = tanh_fast(acc3[ri][2] + b3[m*3 + 2]);
    }
  }
}

// ---------------------------------------------------------------------------
extern "C" void kernel_launch(void* const* d_in, const int* in_sizes, int n_in,
                              void* d_out, int out_size, void* d_ws, size_t ws_size,
                              hipStream_t stream) {
  const float* x0  = (const float*)d_in[0];
  const float* W0a = (const float*)d_in[1];
  const float* b0a = (const float*)d_in[2];
  const float* W0b = (const float*)d_in[3];
  const float* b0b = (const float*)d_in[4];
  const float* W1  = (const float*)d_in[5];
  const float* b1  = (const float*)d_in[6];
  const float* W2  = (const float*)d_in[7];
  const float* b2  = (const float*)d_in[8];
  const float* W3  = (const float*)d_in[9];
  const float* b3  = (const float*)d_in[10];

  char* ws = (char*)d_ws;
  float*  base  = (float*)(ws + WS_BASE);
  bf16_t* W1p   = (bf16_t*)(ws + WS_W1P);
  bf16_t* W2p   = (bf16_t*)(ws + WS_W2P);
  bf16_t* W3p   = (bf16_t*)(ws + WS_W3P);
  float*  basec = (float*)(ws + WS_BASEC);
  float*  wxyc  = (float*)(ws + WS_WXYC);
  int*    idx   = (int*)(ws + WS_IDX);
  int*    lin   = (int*)(ws + WS_LIN);
  float*  F     = (float*)(ws + WS_F);
  int*    Kc    = (int*)(ws + WS_CNT);
  int*    nlin  = (int*)(ws + WS_CNT + 64);
  float*  out   = (float*)d_out;

  prep_a<<<2368, 256, 0, stream>>>(x0, W0a, b0a, b0b, W2, W3, base, W2p, W3p);
  classify_k<<<16, 256, 0, stream>>>(base, W0b, basec, wxyc, idx, lin, Kc, nlin, F);
  prep_b<<<512, 256, 0, stream>>>(W1, base, W0b, idx, lin, Kc, nlin, W1p, F);
  fused_mlp_k<<<2048, 256, 0, stream>>>(basec, wxyc, F, Kc, W1p, W2p, W3p, b1, b2, b3, out);
}